// Round 4
// baseline (306.718 us; speedup 1.0000x reference)
//
#include <hip/hip_runtime.h>
#include <hip/hip_bf16.h>

// LCN spiking net, round 4: single persistent kernel, transposed layout.
//  - Spiking update is identity; only t=T-1 matters -> 32 rows.
//  - Fixed harness floor ~99us (256MB ws poison ~42us + input restore); rounds
//    2-3 showed my remaining ~33us is mostly dispatch overhead + latency.
//  - knn indices are shared across the 32 rows -> store h feature-major
//    h_t[d][32]: each gather is 2x128B coalesced (vs ~50 L1 lines), no LDS
//    staging needed, weights wave-uniform.
//  - One kernel, 256 blocks x 256 threads (tiny VGPR/LDS -> trivially
//    co-resident), hand-rolled monotonic-phase grid barrier with agent-scope
//    atomics + threadfence (cross-XCD visibility). Counter zeroed by a
//    hipMemsetAsync before the launch (graph-capturable).

#define ROWS 32
#define TSTEPS 20
#define D0 14400
#define D1 7200
#define D2 3600
#define D3 1800
#define D4 900
#define D5 450
#define KNB 25

#define NB 256          // blocks (== CUs; co-residency guaranteed, tiny resources)
#define NT 256          // threads per block
#define NWAVES (NB * (NT / 64))   // 1024 waves chip-wide

__device__ __forceinline__ void gbar(unsigned* cnt, unsigned target) {
    __syncthreads();
    if (threadIdx.x == 0) {
        __threadfence();  // release our global writes (agent scope)
        __hip_atomic_fetch_add(cnt, 1u, __ATOMIC_ACQ_REL, __HIP_MEMORY_SCOPE_AGENT);
        while (__hip_atomic_load(cnt, __ATOMIC_ACQUIRE, __HIP_MEMORY_SCOPE_AGENT) < target)
            __builtin_amdgcn_s_sleep(1);
        __threadfence();  // acquire others' writes
    }
    __syncthreads();
}

// One LCN layer in transposed layout: pout[j][r] = b[j] + sum_k pin[knn[j][k]][r]*w[j][k]
// Wave = 2 outputs (jj) x 32 rows (r): gathers are 2x128B coalesced.
__device__ __forceinline__ void layer_t(const float* __restrict__ pin,
                                        float* __restrict__ pout,
                                        const float* __restrict__ w,
                                        const float* __restrict__ bvec,
                                        const int* __restrict__ knn,
                                        int dout_half, int wv, int r, int jj)
{
#pragma unroll 1
    for (int jp = wv; jp < dout_half; jp += NWAVES) {
        const int j = (jp << 1) + jj;
        const int*   kn = knn + j * KNB;
        const float* ww = w   + j * KNB;
        float acc = bvec[j];
#pragma unroll
        for (int k = 0; k < KNB; ++k)
            acc += pin[(kn[k] << 5) + r] * ww[k];
        pout[(j << 5) + r] = acc;
    }
}

__global__ __launch_bounds__(NT)
void lcn_persistent(const float* __restrict__ x,
                    const float* __restrict__ w0, const float* __restrict__ b0, const int* __restrict__ knn0,
                    const float* __restrict__ w1, const float* __restrict__ b1, const int* __restrict__ knn1,
                    const float* __restrict__ w2, const float* __restrict__ b2, const int* __restrict__ knn2,
                    const float* __restrict__ w3, const float* __restrict__ b3, const int* __restrict__ knn3,
                    const float* __restrict__ w4, const float* __restrict__ b4, const int* __restrict__ knn4,
                    const float* __restrict__ Wfc, const float* __restrict__ bfc,
                    float* __restrict__ ws, unsigned* __restrict__ bar,
                    float* __restrict__ out)
{
    // ws layout (floats)
    float* xt = ws;                    // [D0][32]
    float* h1 = xt + D0 * ROWS;        // [D1][32]
    float* h2 = h1 + D1 * ROWS;        // [D2][32]
    float* h3 = h2 + D2 * ROWS;        // [D3][32]
    float* h4 = h3 + D3 * ROWS;        // [D4][32]
    float* h5 = h4 + D4 * ROWS;        // [D5][32]

    const int lane = threadIdx.x & 63;
    const int r    = lane & 31;        // batch row
    const int jj   = lane >> 5;        // which of 2 outputs in this wave
    const int wv   = (blockIdx.x << 2) + (threadIdx.x >> 6);  // global wave id
    const int gid  = blockIdx.x * NT + threadIdx.x;

    // stage T: transpose x[:, T-1, :] -> xt[c][r]
    // writes coalesced; reads strided (cheap: 1.8 MB total, ~0.8us chip-wide)
#pragma unroll 1
    for (int i = gid; i < D0 * ROWS; i += NB * NT) {
        const int c = i >> 5;
        const int rr = i & 31;
        xt[i] = x[(size_t)rr * (TSTEPS * D0) + (size_t)(TSTEPS - 1) * D0 + c];
    }
    gbar(bar, 1 * NB);

    layer_t(xt, h1, w0, b0, knn0, D1 / 2, wv, r, jj);
    gbar(bar, 2 * NB);

    layer_t(h1, h2, w1, b1, knn1, D2 / 2, wv, r, jj);
    gbar(bar, 3 * NB);

    layer_t(h2, h3, w2, b2, knn2, D3 / 2, wv, r, jj);
    gbar(bar, 4 * NB);

    layer_t(h3, h4, w3, b3, knn3, D4 / 2, wv, r, jj);
    gbar(bar, 5 * NB);

    layer_t(h4, h5, w4, b4, knn4, D5 / 2, wv, r, jj);
    gbar(bar, 6 * NB);

    // FC on block 0: out[r][o] = bfc[o] + sum_i h5[i][r]*Wfc[i][o]
    if (blockIdx.x == 0) {
        __shared__ float red[NT];
        const int sub = threadIdx.x & 63;   // (o,r)
        const int rr  = sub & 31;
        const int oo  = sub >> 5;
        const int seg = threadIdx.x >> 6;   // 4 segments over i
        float p = 0.0f;
#pragma unroll 1
        for (int i = seg; i < D5; i += 4)
            p += h5[(i << 5) + rr] * Wfc[i * 2 + oo];
        red[threadIdx.x] = p;
        __syncthreads();
        if (threadIdx.x < 64) {
            float s = red[threadIdx.x] + red[threadIdx.x + 64] +
                      red[threadIdx.x + 128] + red[threadIdx.x + 192];
            out[rr * 2 + oo] = s + bfc[oo];
        }
    }
}

extern "C" void kernel_launch(void* const* d_in, const int* in_sizes, int n_in,
                              void* d_out, int out_size, void* d_ws, size_t ws_size,
                              hipStream_t stream)
{
    const float* x    = (const float*)d_in[0];
    const float* w0   = (const float*)d_in[1];
    const float* b0   = (const float*)d_in[2];
    const int*   knn0 = (const int*)  d_in[3];
    const float* w1   = (const float*)d_in[4];
    const float* b1   = (const float*)d_in[5];
    const int*   knn1 = (const int*)  d_in[6];
    const float* w2   = (const float*)d_in[7];
    const float* b2   = (const float*)d_in[8];
    const int*   knn2 = (const int*)  d_in[9];
    const float* w3   = (const float*)d_in[10];
    const float* b3   = (const float*)d_in[11];
    const int*   knn3 = (const int*)  d_in[12];
    const float* w4   = (const float*)d_in[13];
    const float* b4   = (const float*)d_in[14];
    const int*   knn4 = (const int*)  d_in[15];
    const float* Wfc  = (const float*)d_in[16];
    const float* bfc  = (const float*)d_in[17];
    float* out = (float*)d_out;

    // ws: transposed activations (907200 floats = 3.63 MB), then barrier counter
    float*    ws  = (float*)d_ws;
    const size_t bar_off = (size_t)(D0 + D1 + D2 + D3 + D4 + D5) * ROWS * sizeof(float);
    unsigned* bar = (unsigned*)((char*)d_ws + bar_off);

    // zero the barrier counter (ws is poisoned 0xAA before every timed call)
    hipMemsetAsync(bar, 0, 64, stream);

    lcn_persistent<<<dim3(NB), dim3(NT), 0, stream>>>(
        x,
        w0, b0, knn0,
        w1, b1, knn1,
        w2, b2, knn2,
        w3, b3, knn3,
        w4, b4, knn4,
        Wfc, bfc,
        ws, bar, out);
}

// Round 5
// 128.713 us; speedup vs baseline: 2.3830x; 2.3830x over previous
//
#include <hip/hip_runtime.h>
#include <hip/hip_bf16.h>

// LCN spiking net, round 5: multi-dispatch + transposed layout.
//  - Spiking update is identity; only t=T-1 matters -> 32 rows.
//  - Round 4 lesson: software grid barriers cost ~35us each on gfx950
//    (cross-XCD line ping-pong + threadfence L2 invalidates). Multi-dispatch
//    boundaries (~2-4us) are strictly cheaper -> back to 5 dispatches.
//  - Round 4 keep: feature-major h_t[d][32] so the knn gather (indices shared
//    across rows) is 2x128B coalesced; weights near-wave-uniform.
//  - Layer0 stages the 57.6KB x-row in LDS (block per row-chunk) and writes
//    transposed; layers 1-3 are pure transposed gathers; layer4 fuses the
//    450->2 FC via LDS reduction + 64 atomicAdds (d_out pre-zeroed by
//    hipMemsetAsync, bias injected by block 0).

#define ROWS 32
#define TSTEPS 20
#define D0 14400
#define D1 7200
#define D2 3600
#define D3 1800
#define D4 900
#define D5 450
#define KNB 25

// K1: layer 0. Grid (8, ROWS), block 256. Stage x row in LDS, gather, write h1t.
__global__ __launch_bounds__(256)
void l0_stage(const float* __restrict__ x, float* __restrict__ h1t,
              const float* __restrict__ w, const float* __restrict__ bvec,
              const int* __restrict__ knn)
{
    __shared__ float s[D0];   // 57.6 KB
    const int r = blockIdx.y;
    const float* xrow = x + ((size_t)r * TSTEPS + (TSTEPS - 1)) * (size_t)D0;

    const float4* src = reinterpret_cast<const float4*>(xrow);
    float4* dst = reinterpret_cast<float4*>(s);
#pragma unroll 1
    for (int i = threadIdx.x; i < D0 / 4; i += 256)
        dst[i] = src[i];
    __syncthreads();

    const int j0 = blockIdx.x * 900;
#pragma unroll 1
    for (int j = j0 + threadIdx.x; j < j0 + 900; j += 256) {
        const int*   kn = knn + j * KNB;
        const float* ww = w   + j * KNB;
        float acc = bvec[j];
#pragma unroll
        for (int k = 0; k < KNB; ++k)
            acc += s[kn[k]] * ww[k];
        h1t[(j << 5) + r] = acc;   // transposed write
    }
}

// Transposed gather layer: pout[j][r] = b[j] + sum_k pin[knn[j][k]][r]*w[j][k]
// Wave = 2 outputs x 32 rows; each gather touches 2 contiguous 128B lines.
__global__ __launch_bounds__(256)
void layer_t_k(const float* __restrict__ pin, float* __restrict__ pout,
               const float* __restrict__ w, const float* __restrict__ bvec,
               const int* __restrict__ knn, int npairs)
{
    const int lane = threadIdx.x & 63;
    const int r  = lane & 31;
    const int jj = lane >> 5;
    const int nw = gridDim.x << 2;
#pragma unroll 1
    for (int jp = (blockIdx.x << 2) + (threadIdx.x >> 6); jp < npairs; jp += nw) {
        const int j = (jp << 1) + jj;
        const int*   kn = knn + j * KNB;
        const float* ww = w   + j * KNB;
        float acc = bvec[j];
#pragma unroll
        for (int k = 0; k < KNB; ++k)
            acc += pin[(kn[k] << 5) + r] * ww[k];
        pout[(j << 5) + r] = acc;
    }
}

// K5: layer 4 (900->450) fused with FC (450->2).
// Per-block partial FC in LDS, then 64 atomicAdds to pre-zeroed out.
__global__ __launch_bounds__(256)
void l4_fc(const float* __restrict__ h4t,
           const float* __restrict__ w, const float* __restrict__ bvec,
           const int* __restrict__ knn,
           const float* __restrict__ Wfc, const float* __restrict__ bfc,
           float* __restrict__ out)
{
    __shared__ float sacc[64];   // [r][o]
    if (threadIdx.x < 64)
        sacc[threadIdx.x] = (blockIdx.x == 0) ? bfc[threadIdx.x & 1] : 0.0f;
    __syncthreads();

    const int lane = threadIdx.x & 63;
    const int r  = lane & 31;
    const int jj = lane >> 5;
    const int nw = gridDim.x << 2;
    float c0 = 0.0f, c1 = 0.0f;
#pragma unroll 1
    for (int jp = (blockIdx.x << 2) + (threadIdx.x >> 6); jp < D5 / 2; jp += nw) {
        const int j = (jp << 1) + jj;
        const int*   kn = knn + j * KNB;
        const float* ww = w   + j * KNB;
        float acc = bvec[j];
#pragma unroll
        for (int k = 0; k < KNB; ++k)
            acc += h4t[(kn[k] << 5) + r] * ww[k];
        c0 += acc * Wfc[j * 2 + 0];
        c1 += acc * Wfc[j * 2 + 1];
    }
    atomicAdd(&sacc[(r << 1) + 0], c0);
    atomicAdd(&sacc[(r << 1) + 1], c1);
    __syncthreads();
    if (threadIdx.x < 64)
        atomicAdd(&out[threadIdx.x], sacc[threadIdx.x]);
}

extern "C" void kernel_launch(void* const* d_in, const int* in_sizes, int n_in,
                              void* d_out, int out_size, void* d_ws, size_t ws_size,
                              hipStream_t stream)
{
    const float* x    = (const float*)d_in[0];
    const float* w0   = (const float*)d_in[1];
    const float* b0   = (const float*)d_in[2];
    const int*   knn0 = (const int*)  d_in[3];
    const float* w1   = (const float*)d_in[4];
    const float* b1   = (const float*)d_in[5];
    const int*   knn1 = (const int*)  d_in[6];
    const float* w2   = (const float*)d_in[7];
    const float* b2   = (const float*)d_in[8];
    const int*   knn2 = (const int*)  d_in[9];
    const float* w3   = (const float*)d_in[10];
    const float* b3   = (const float*)d_in[11];
    const int*   knn3 = (const int*)  d_in[12];
    const float* w4   = (const float*)d_in[13];
    const float* b4   = (const float*)d_in[14];
    const int*   knn4 = (const int*)  d_in[15];
    const float* Wfc  = (const float*)d_in[16];
    const float* bfc  = (const float*)d_in[17];
    float* out = (float*)d_out;

    // transposed intermediates in ws (floats): h1t[D1][32] | h2t | h3t | h4t
    float* h1t = (float*)d_ws;
    float* h2t = h1t + (size_t)D1 * ROWS;
    float* h3t = h2t + (size_t)D2 * ROWS;
    float* h4t = h3t + (size_t)D3 * ROWS;

    // out is re-poisoned 0xAA before every timed call; FC accumulates into it.
    hipMemsetAsync(out, 0, (size_t)out_size * sizeof(float), stream);

    // layer 0: x[:,T-1,:] -> h1t
    l0_stage<<<dim3(D1 / 900, ROWS), dim3(256), 0, stream>>>(x, h1t, w0, b0, knn0);

    // layer 1: h1t -> h2t  (1800 output-pairs, 1 pair/wave)
    layer_t_k<<<dim3(450), dim3(256), 0, stream>>>(h1t, h2t, w1, b1, knn1, D2 / 2);

    // layer 2: h2t -> h3t  (900 pairs)
    layer_t_k<<<dim3(225), dim3(256), 0, stream>>>(h2t, h3t, w2, b2, knn2, D3 / 2);

    // layer 3: h3t -> h4t  (450 pairs)
    layer_t_k<<<dim3(113), dim3(256), 0, stream>>>(h3t, h4t, w3, b3, knn3, D4 / 2);

    // layer 4 + FC: h4t -> out  (225 pairs)
    l4_fc<<<dim3(57), dim3(256), 0, stream>>>(h4t, w4, b4, knn4, Wfc, bfc, out);
}